// Round 1
// baseline (130.499 us; speedup 1.0000x reference)
//
#include <hip/hip_runtime.h>

#define KK 4
#define TT 100000
#define DIM 128
#define NCLS 100
#define MARGIN_F 0.2f
#define EPS_F 1e-8f

__global__ __launch_bounds__(256) void margin_main(
    const float* __restrict__ batch,
    const int* __restrict__ labels,
    const int* __restrict__ triplets,
    const float* __restrict__ beta,
    float* __restrict__ ws)  // ws[0..3] = totals, ws[4..7] = counts
{
    __shared__ float s_tot[KK];
    __shared__ float s_cnt[KK];
    const int tid = threadIdx.x;
    if (tid < KK) { s_tot[tid] = 0.f; s_cnt[tid] = 0.f; }
    __syncthreads();

    const int lane = tid & 63;
    const int wave_in_block = tid >> 6;
    const int waves_per_block = blockDim.x >> 6;
    const long long wave_id = (long long)blockIdx.x * waves_per_block + wave_in_block;
    const long long n_waves = (long long)gridDim.x * waves_per_block;
    const long long n_trip = (long long)KK * TT;

    float loc_tot[KK] = {0.f, 0.f, 0.f, 0.f};
    float loc_cnt[KK] = {0.f, 0.f, 0.f, 0.f};

    for (long long idx = wave_id; idx < n_trip; idx += n_waves) {
        const int k = (int)(idx / TT);
        const int* tp = triplets + idx * 3;
        const int i0 = tp[0];
        const int i1 = tp[1];
        const int i2 = tp[2];

        const float* a = batch + ((long long)(i0 * KK + k)) * DIM;
        const float* p = batch + ((long long)(i1 * KK + k)) * DIM;
        const float* g = batch + ((long long)(i2 * KK + k)) * DIM;

        const float2 av = *(const float2*)(a + lane * 2);
        const float2 pv = *(const float2*)(p + lane * 2);
        const float2 gv = *(const float2*)(g + lane * 2);

        const float dap0 = av.x - pv.x, dap1 = av.y - pv.y;
        const float dan0 = av.x - gv.x, dan1 = av.y - gv.y;
        float sap = dap0 * dap0 + dap1 * dap1;
        float san = dan0 * dan0 + dan1 * dan1;

        #pragma unroll
        for (int off = 32; off; off >>= 1) {
            sap += __shfl_xor(sap, off);
            san += __shfl_xor(san, off);
        }

        if (lane == 0) {
            const float d_ap = sqrtf(sap + EPS_F);
            const float d_an = sqrtf(san + EPS_F);
            const float b = beta[k * NCLS + labels[i0]];
            const float pl = fmaxf(d_ap - b + MARGIN_F, 0.f);
            const float nl = fmaxf(b - d_an + MARGIN_F, 0.f);
            loc_tot[k] += pl + nl;
            loc_cnt[k] += (pl > 0.f || nl > 0.f) ? 1.f : 0.f;
        }
    }

    if (lane == 0) {
        #pragma unroll
        for (int k2 = 0; k2 < KK; ++k2) {
            if (loc_tot[k2] != 0.f || loc_cnt[k2] != 0.f) {
                atomicAdd(&s_tot[k2], loc_tot[k2]);
                atomicAdd(&s_cnt[k2], loc_cnt[k2]);
            }
        }
    }
    __syncthreads();

    if (tid < KK) {
        if (s_tot[tid] != 0.f) atomicAdd(&ws[tid], s_tot[tid]);
        if (s_cnt[tid] != 0.f) atomicAdd(&ws[KK + tid], s_cnt[tid]);
    }
}

__global__ void margin_final(const float* __restrict__ ws, float* __restrict__ out) {
    if (threadIdx.x == 0 && blockIdx.x == 0) {
        float acc = 0.f;
        #pragma unroll
        for (int k = 0; k < KK; ++k) {
            const float tot = ws[k];
            const float cnt = ws[KK + k];
            const float lk = (cnt == 0.f) ? tot : tot / fmaxf(cnt, 1.f);
            acc += lk;
        }
        out[0] = acc / (float)KK;
    }
}

extern "C" void kernel_launch(void* const* d_in, const int* in_sizes, int n_in,
                              void* d_out, int out_size, void* d_ws, size_t ws_size,
                              hipStream_t stream) {
    const float* batch    = (const float*)d_in[0];
    const int*   labels   = (const int*)d_in[1];
    const int*   triplets = (const int*)d_in[2];
    const float* beta     = (const float*)d_in[3];
    float* ws = (float*)d_ws;

    hipMemsetAsync(d_ws, 0, 2 * KK * sizeof(float), stream);

    const int blocks = 2048;
    margin_main<<<blocks, 256, 0, stream>>>(batch, labels, triplets, beta, ws);
    margin_final<<<1, 64, 0, stream>>>(ws, (float*)d_out);
}

// Round 2
// 61.114 us; speedup vs baseline: 2.1353x; 2.1353x over previous
//
#include <hip/hip_runtime.h>

#define KK 4
#define TT 100000
#define NCLS 100
#define MARGIN_F 0.2f
#define EPS_F 1e-8f

#define NBLOCKS 2048
#define GROUPS_PER_K (NBLOCKS * 8)   // 8 groups/wave, 1 wave per k per block
#define NCOPY 8                      // spread global atomics over 8 copies

// ws layout: ws[c*8 + j], j in [0,8): j<4 totals, j>=4 counts; c in [0,NCOPY)
__global__ __launch_bounds__(256) void margin_main(
    const float* __restrict__ batch,
    const int* __restrict__ labels,
    const int* __restrict__ triplets,
    const float* __restrict__ beta,
    float* __restrict__ ws)
{
    __shared__ float s_red[8];
    const int tid  = threadIdx.x;
    const int lane = tid & 63;
    const int k    = tid >> 6;        // wave in block == k (uniform -> SGPR)
    const int g    = lane >> 3;       // group in wave (8 lanes/triplet)
    const int s    = lane & 7;        // sub-lane in group

    const int t0 = blockIdx.x * 8 + g;
    const int* __restrict__ trip_k   = triplets + k * (TT * 3);
    const float* __restrict__ beta_k = beta + k * NCLS;

    float lt = 0.f, lc = 0.f;

    for (int t = t0; t < TT; t += GROUPS_PER_K) {
        const int* tp = trip_k + t * 3;
        const int i0 = tp[0];
        const int i1 = tp[1];
        const int i2 = tp[2];

        // row of batch[n, k, :]: byte offset n*2048 + k*512
        const float* a = batch + (((i0 << 2) + k) << 7);
        const float* p = batch + (((i1 << 2) + k) << 7);
        const float* n = batch + (((i2 << 2) + k) << 7);

        float sap = 0.f, san = 0.f;
        #pragma unroll
        for (int i = 0; i < 4; ++i) {
            const int off = s * 4 + i * 32;           // floats
            const float4 av = *(const float4*)(a + off);
            const float4 pv = *(const float4*)(p + off);
            const float4 nv = *(const float4*)(n + off);
            float d;
            d = av.x - pv.x; sap += d * d;
            d = av.y - pv.y; sap += d * d;
            d = av.z - pv.z; sap += d * d;
            d = av.w - pv.w; sap += d * d;
            d = av.x - nv.x; san += d * d;
            d = av.y - nv.y; san += d * d;
            d = av.z - nv.z; san += d * d;
            d = av.w - nv.w; san += d * d;
        }

        // 3-level butterfly within the 8-lane group
        #pragma unroll
        for (int o = 4; o; o >>= 1) {
            sap += __shfl_xor(sap, o);
            san += __shfl_xor(san, o);
        }

        if (s == 0) {
            const float d_ap = sqrtf(sap + EPS_F);
            const float d_an = sqrtf(san + EPS_F);
            const float b  = beta_k[labels[i0]];
            const float pl = fmaxf(d_ap - b + MARGIN_F, 0.f);
            const float nl = fmaxf(b - d_an + MARGIN_F, 0.f);
            lt += pl + nl;
            lc += (pl > 0.f || nl > 0.f) ? 1.f : 0.f;
        }
    }

    // combine the 8 s==0 lanes of this wave (others hold zeros)
    #pragma unroll
    for (int o = 8; o <= 32; o <<= 1) {
        lt += __shfl_xor(lt, o);
        lc += __shfl_xor(lc, o);
    }
    if (lane == 0) { s_red[k] = lt; s_red[4 + k] = lc; }
    __syncthreads();

    if (tid < 8) {
        const int c = blockIdx.x & (NCOPY - 1);
        atomicAdd(&ws[c * 8 + tid], s_red[tid]);
    }
}

__global__ void margin_final(const float* __restrict__ ws, float* __restrict__ out) {
    if (threadIdx.x == 0 && blockIdx.x == 0) {
        float acc = 0.f;
        #pragma unroll
        for (int k = 0; k < KK; ++k) {
            float tot = 0.f, cnt = 0.f;
            #pragma unroll
            for (int c = 0; c < NCOPY; ++c) {
                tot += ws[c * 8 + k];
                cnt += ws[c * 8 + 4 + k];
            }
            const float lk = (cnt == 0.f) ? tot : tot / fmaxf(cnt, 1.f);
            acc += lk;
        }
        out[0] = acc / (float)KK;
    }
}

extern "C" void kernel_launch(void* const* d_in, const int* in_sizes, int n_in,
                              void* d_out, int out_size, void* d_ws, size_t ws_size,
                              hipStream_t stream) {
    const float* batch    = (const float*)d_in[0];
    const int*   labels   = (const int*)d_in[1];
    const int*   triplets = (const int*)d_in[2];
    const float* beta     = (const float*)d_in[3];
    float* ws = (float*)d_ws;

    hipMemsetAsync(d_ws, 0, NCOPY * 8 * sizeof(float), stream);

    margin_main<<<NBLOCKS, 256, 0, stream>>>(batch, labels, triplets, beta, ws);
    margin_final<<<1, 64, 0, stream>>>(ws, (float*)d_out);
}

// Round 3
// 50.975 us; speedup vs baseline: 2.5600x; 1.1989x over previous
//
#include <hip/hip_runtime.h>

#define KK 4
#define TT 100000
#define NCLS 100
#define MARGIN_F 0.2f
#define EPS_F 1e-8f

#define NBLOCKS 2048
#define NXCD 8
// per k: 2 XCDs * 256 blocks * 4 waves * 8 groups = 16384 triplet-groups
#define GROUPS_PER_K (512 * 4 * 8)
#define NCOPY 8

// ws layout: ws[c*8 + j], j<4: totals, j>=4: counts
__global__ __launch_bounds__(256) void margin_main(
    const float* __restrict__ batch,
    const int* __restrict__ labels,
    const int* __restrict__ triplets,
    const float* __restrict__ beta,
    float* __restrict__ ws)
{
    __shared__ float s_red[8];
    const int tid  = threadIdx.x;
    const int lane = tid & 63;
    const int wave = tid >> 6;
    const int g    = lane >> 3;       // group in wave (8 lanes/triplet)
    const int s    = lane & 7;        // sub-lane in group

    // XCD-pinned k: blocks round-robin over 8 XCDs; 2 XCDs own each k.
    const int xcd      = blockIdx.x & (NXCD - 1);
    const int k        = xcd >> 1;                                  // 0..3
    const int blk_in_k = ((xcd & 1) << 8) | (blockIdx.x >> 3);      // 0..511

    const int g0 = blk_in_k * 32 + wave * 8 + g;

    const int* __restrict__ trip_k   = triplets + k * (TT * 3);
    const float* __restrict__ beta_k = beta + k * NCLS;

    float lt = 0.f, lc = 0.f;

    for (int t = g0; t < TT; t += GROUPS_PER_K) {
        const int* tp = trip_k + t * 3;
        const int i0 = tp[0];
        const int i1 = tp[1];
        const int i2 = tp[2];

        // row of batch[n, k, :]: float offset (n*4 + k) * 128
        const float* a = batch + (((i0 << 2) + k) << 7);
        const float* p = batch + (((i1 << 2) + k) << 7);
        const float* n = batch + (((i2 << 2) + k) << 7);

        float sap = 0.f, san = 0.f;
        #pragma unroll
        for (int i = 0; i < 4; ++i) {
            const int off = s * 4 + i * 32;           // floats
            const float4 av = *(const float4*)(a + off);
            const float4 pv = *(const float4*)(p + off);
            const float4 nv = *(const float4*)(n + off);
            float d;
            d = av.x - pv.x; sap += d * d;
            d = av.y - pv.y; sap += d * d;
            d = av.z - pv.z; sap += d * d;
            d = av.w - pv.w; sap += d * d;
            d = av.x - nv.x; san += d * d;
            d = av.y - nv.y; san += d * d;
            d = av.z - nv.z; san += d * d;
            d = av.w - nv.w; san += d * d;
        }

        // 3-level butterfly within the 8-lane group
        #pragma unroll
        for (int o = 4; o; o >>= 1) {
            sap += __shfl_xor(sap, o);
            san += __shfl_xor(san, o);
        }

        if (s == 0) {
            const float d_ap = sqrtf(sap + EPS_F);
            const float d_an = sqrtf(san + EPS_F);
            const float b  = beta_k[labels[i0]];
            const float pl = fmaxf(d_ap - b + MARGIN_F, 0.f);
            const float nl = fmaxf(b - d_an + MARGIN_F, 0.f);
            lt += pl + nl;
            lc += (pl > 0.f || nl > 0.f) ? 1.f : 0.f;
        }
    }

    // combine the 8 s==0 lanes of this wave (others hold zeros)
    #pragma unroll
    for (int o = 8; o <= 32; o <<= 1) {
        lt += __shfl_xor(lt, o);
        lc += __shfl_xor(lc, o);
    }
    if (lane == 0) { s_red[wave] = lt; s_red[4 + wave] = lc; }
    __syncthreads();

    // all 4 waves share the same k in this block: sum them, one atomic pair
    if (tid == 0) {
        const float tot = s_red[0] + s_red[1] + s_red[2] + s_red[3];
        const float cnt = s_red[4] + s_red[5] + s_red[6] + s_red[7];
        const int c = (blockIdx.x >> 3) & (NCOPY - 1);
        atomicAdd(&ws[c * 8 + k], tot);
        atomicAdd(&ws[c * 8 + 4 + k], cnt);
    }
}

__global__ void margin_final(const float* __restrict__ ws, float* __restrict__ out) {
    if (threadIdx.x == 0 && blockIdx.x == 0) {
        float acc = 0.f;
        #pragma unroll
        for (int k = 0; k < KK; ++k) {
            float tot = 0.f, cnt = 0.f;
            #pragma unroll
            for (int c = 0; c < NCOPY; ++c) {
                tot += ws[c * 8 + k];
                cnt += ws[c * 8 + 4 + k];
            }
            const float lk = (cnt == 0.f) ? tot : tot / fmaxf(cnt, 1.f);
            acc += lk;
        }
        out[0] = acc / (float)KK;
    }
}

extern "C" void kernel_launch(void* const* d_in, const int* in_sizes, int n_in,
                              void* d_out, int out_size, void* d_ws, size_t ws_size,
                              hipStream_t stream) {
    const float* batch    = (const float*)d_in[0];
    const int*   labels   = (const int*)d_in[1];
    const int*   triplets = (const int*)d_in[2];
    const float* beta     = (const float*)d_in[3];
    float* ws = (float*)d_ws;

    hipMemsetAsync(d_ws, 0, NCOPY * 8 * sizeof(float), stream);

    margin_main<<<NBLOCKS, 256, 0, stream>>>(batch, labels, triplets, beta, ws);
    margin_final<<<1, 64, 0, stream>>>(ws, (float*)d_out);
}

// Round 4
// 50.966 us; speedup vs baseline: 2.5605x; 1.0002x over previous
//
#include <hip/hip_runtime.h>

#define KK 4
#define TT 100000
#define NCLS 100
#define MARGIN_F 0.2f
#define EPS_F 1e-8f

#define NBLOCKS 2048
#define NXCD 8
#define GROUPS_PER_K (512 * 4 * 8)   // per k: 512 blocks * 4 waves * 8 groups
#define NCOPY 8
#define ACC_BYTES 256                // ws[0..63] accumulators, fp16 batch after

typedef _Float16 h2 __attribute__((ext_vector_type(2)));
struct H8 { h2 a, b, c, d; };        // 16 B = 8 halves

// fp32 batch (N*K*DIM = 2M floats) -> fp16, same layout
__global__ __launch_bounds__(256) void convert_fp16(
    const float* __restrict__ src, _Float16* __restrict__ dst)
{
    const int i = blockIdx.x * blockDim.x + threadIdx.x;   // 0..262143
    const float4 v0 = ((const float4*)src)[i * 2];
    const float4 v1 = ((const float4*)src)[i * 2 + 1];
    H8 o;
    o.a = h2{(_Float16)v0.x, (_Float16)v0.y};
    o.b = h2{(_Float16)v0.z, (_Float16)v0.w};
    o.c = h2{(_Float16)v1.x, (_Float16)v1.y};
    o.d = h2{(_Float16)v1.z, (_Float16)v1.w};
    ((H8*)dst)[i] = o;
}

// ws layout: ws[c*8 + j], j<4: totals, j>=4: counts
__global__ __launch_bounds__(256) void margin_main(
    const _Float16* __restrict__ hb,
    const int* __restrict__ labels,
    const int* __restrict__ triplets,
    const float* __restrict__ beta,
    float* __restrict__ ws)
{
    __shared__ float s_red[8];
    const int tid  = threadIdx.x;
    const int lane = tid & 63;
    const int wave = tid >> 6;
    const int g    = lane >> 3;       // group in wave (8 lanes/triplet)
    const int s    = lane & 7;        // sub-lane in group

    // XCD-pinned k: blocks round-robin over 8 XCDs; 2 XCDs own each k.
    const int xcd      = blockIdx.x & (NXCD - 1);
    const int k        = xcd >> 1;                               // 0..3
    const int blk_in_k = ((xcd & 1) << 8) | (blockIdx.x >> 3);   // 0..511

    const int g0 = blk_in_k * 32 + wave * 8 + g;

    const int* __restrict__ trip_k   = triplets + k * (TT * 3);
    const float* __restrict__ beta_k = beta + k * NCLS;
    const int co0 = s * 8;            // half offset, chunk 0
    const int co1 = 64 + s * 8;       // half offset, chunk 1

    float lt = 0.f, lc = 0.f;

    for (int t = g0; t < TT; t += GROUPS_PER_K) {
        const int* tp = trip_k + t * 3;
        const int i0 = tp[0];
        const int i1 = tp[1];
        const int i2 = tp[2];

        // fp16 row of batch[n, k, :]: half offset (n*4 + k) * 128
        const _Float16* a = hb + (((i0 << 2) + k) << 7);
        const _Float16* p = hb + (((i1 << 2) + k) << 7);
        const _Float16* n = hb + (((i2 << 2) + k) << 7);

        // issue all 6 16-B loads up front (MLP)
        const H8 a0 = *(const H8*)(a + co0);
        const H8 a1 = *(const H8*)(a + co1);
        const H8 p0 = *(const H8*)(p + co0);
        const H8 p1 = *(const H8*)(p + co1);
        const H8 n0 = *(const H8*)(n + co0);
        const H8 n1 = *(const H8*)(n + co1);

        float sap = 0.f, san = 0.f;
        h2 d;
        d = a0.a - p0.a; sap = __builtin_amdgcn_fdot2(d, d, sap, false);
        d = a0.b - p0.b; sap = __builtin_amdgcn_fdot2(d, d, sap, false);
        d = a0.c - p0.c; sap = __builtin_amdgcn_fdot2(d, d, sap, false);
        d = a0.d - p0.d; sap = __builtin_amdgcn_fdot2(d, d, sap, false);
        d = a1.a - p1.a; sap = __builtin_amdgcn_fdot2(d, d, sap, false);
        d = a1.b - p1.b; sap = __builtin_amdgcn_fdot2(d, d, sap, false);
        d = a1.c - p1.c; sap = __builtin_amdgcn_fdot2(d, d, sap, false);
        d = a1.d - p1.d; sap = __builtin_amdgcn_fdot2(d, d, sap, false);

        d = a0.a - n0.a; san = __builtin_amdgcn_fdot2(d, d, san, false);
        d = a0.b - n0.b; san = __builtin_amdgcn_fdot2(d, d, san, false);
        d = a0.c - n0.c; san = __builtin_amdgcn_fdot2(d, d, san, false);
        d = a0.d - n0.d; san = __builtin_amdgcn_fdot2(d, d, san, false);
        d = a1.a - n1.a; san = __builtin_amdgcn_fdot2(d, d, san, false);
        d = a1.b - n1.b; san = __builtin_amdgcn_fdot2(d, d, san, false);
        d = a1.c - n1.c; san = __builtin_amdgcn_fdot2(d, d, san, false);
        d = a1.d - n1.d; san = __builtin_amdgcn_fdot2(d, d, san, false);

        // 3-level butterfly within the 8-lane group
        #pragma unroll
        for (int o = 4; o; o >>= 1) {
            sap += __shfl_xor(sap, o);
            san += __shfl_xor(san, o);
        }

        if (s == 0) {
            const float d_ap = sqrtf(sap + EPS_F);
            const float d_an = sqrtf(san + EPS_F);
            const float b  = beta_k[labels[i0]];
            const float pl = fmaxf(d_ap - b + MARGIN_F, 0.f);
            const float nl = fmaxf(b - d_an + MARGIN_F, 0.f);
            lt += pl + nl;
            lc += (pl > 0.f || nl > 0.f) ? 1.f : 0.f;
        }
    }

    // combine the 8 s==0 lanes of this wave (others hold zeros)
    #pragma unroll
    for (int o = 8; o <= 32; o <<= 1) {
        lt += __shfl_xor(lt, o);
        lc += __shfl_xor(lc, o);
    }
    if (lane == 0) { s_red[wave] = lt; s_red[4 + wave] = lc; }
    __syncthreads();

    if (tid == 0) {
        const float tot = s_red[0] + s_red[1] + s_red[2] + s_red[3];
        const float cnt = s_red[4] + s_red[5] + s_red[6] + s_red[7];
        const int c = (blockIdx.x >> 3) & (NCOPY - 1);
        atomicAdd(&ws[c * 8 + k], tot);
        atomicAdd(&ws[c * 8 + 4 + k], cnt);
    }
}

__global__ void margin_final(const float* __restrict__ ws, float* __restrict__ out) {
    if (threadIdx.x == 0 && blockIdx.x == 0) {
        float acc = 0.f;
        #pragma unroll
        for (int k = 0; k < KK; ++k) {
            float tot = 0.f, cnt = 0.f;
            #pragma unroll
            for (int c = 0; c < NCOPY; ++c) {
                tot += ws[c * 8 + k];
                cnt += ws[c * 8 + 4 + k];
            }
            const float lk = (cnt == 0.f) ? tot : tot / fmaxf(cnt, 1.f);
            acc += lk;
        }
        out[0] = acc / (float)KK;
    }
}

extern "C" void kernel_launch(void* const* d_in, const int* in_sizes, int n_in,
                              void* d_out, int out_size, void* d_ws, size_t ws_size,
                              hipStream_t stream) {
    const float* batch    = (const float*)d_in[0];
    const int*   labels   = (const int*)d_in[1];
    const int*   triplets = (const int*)d_in[2];
    const float* beta     = (const float*)d_in[3];

    float*     ws = (float*)d_ws;
    _Float16*  hb = (_Float16*)((char*)d_ws + ACC_BYTES);

    hipMemsetAsync(d_ws, 0, NCOPY * 8 * sizeof(float), stream);

    // 2M floats -> fp16: 262144 threads, 8 elems each
    convert_fp16<<<1024, 256, 0, stream>>>(batch, hb);

    margin_main<<<NBLOCKS, 256, 0, stream>>>(hb, labels, triplets, beta, ws);
    margin_final<<<1, 64, 0, stream>>>(ws, (float*)d_out);
}

// Round 5
// 43.915 us; speedup vs baseline: 2.9716x; 1.1606x over previous
//
#include <hip/hip_runtime.h>

#define KK 4
#define TT 100000
#define NCLS 100
#define NN 4096
#define MARGIN_F 0.2f
#define EPS_F 1e-8f

#define NBLOCKS 2048
#define NXCD 8
#define STRIDE_K (512 * 4 * 8)   // triplet-groups per k provided by the grid
#define NCOPY 8
#define ACC_BYTES 256
#define HB_BYTES (NN * KK * 128 * 2)   // fp16 batch, 4 MB

typedef _Float16 h2 __attribute__((ext_vector_type(2)));
struct H8 { h2 a, b, c, d; };        // 16 B = 8 halves

// fp32->fp16 convert + beta-lookup table + ws accumulator zeroing
__global__ __launch_bounds__(256) void prep(
    const float* __restrict__ src, const int* __restrict__ labels,
    const float* __restrict__ beta,
    _Float16* __restrict__ dst, float* __restrict__ bl, float* __restrict__ ws)
{
    const int i = blockIdx.x * blockDim.x + threadIdx.x;   // 0..262143
    const float4 v0 = ((const float4*)src)[i * 2];
    const float4 v1 = ((const float4*)src)[i * 2 + 1];
    H8 o;
    o.a = h2{(_Float16)v0.x, (_Float16)v0.y};
    o.b = h2{(_Float16)v0.z, (_Float16)v0.w};
    o.c = h2{(_Float16)v1.x, (_Float16)v1.y};
    o.d = h2{(_Float16)v1.z, (_Float16)v1.w};
    ((H8*)dst)[i] = o;

    if (i < KK * NN) {                      // bl[k][n] = beta[k][labels[n]]
        const int n = i >> 2, k = i & 3;
        bl[k * NN + n] = beta[k * NCLS + labels[n]];
    }
    if (i < NCOPY * 8) ws[i] = 0.f;
}

__device__ __forceinline__ void tri_compute(
    const H8& a0, const H8& a1, const H8& p0, const H8& p1,
    const H8& n0, const H8& n1, const float b, const int s,
    float& lt, float& lc)
{
    float sap = 0.f, san = 0.f;
    h2 d;
    d = a0.a - p0.a; sap = __builtin_amdgcn_fdot2(d, d, sap, false);
    d = a0.b - p0.b; sap = __builtin_amdgcn_fdot2(d, d, sap, false);
    d = a0.c - p0.c; sap = __builtin_amdgcn_fdot2(d, d, sap, false);
    d = a0.d - p0.d; sap = __builtin_amdgcn_fdot2(d, d, sap, false);
    d = a1.a - p1.a; sap = __builtin_amdgcn_fdot2(d, d, sap, false);
    d = a1.b - p1.b; sap = __builtin_amdgcn_fdot2(d, d, sap, false);
    d = a1.c - p1.c; sap = __builtin_amdgcn_fdot2(d, d, sap, false);
    d = a1.d - p1.d; sap = __builtin_amdgcn_fdot2(d, d, sap, false);

    d = a0.a - n0.a; san = __builtin_amdgcn_fdot2(d, d, san, false);
    d = a0.b - n0.b; san = __builtin_amdgcn_fdot2(d, d, san, false);
    d = a0.c - n0.c; san = __builtin_amdgcn_fdot2(d, d, san, false);
    d = a0.d - n0.d; san = __builtin_amdgcn_fdot2(d, d, san, false);
    d = a1.a - n1.a; san = __builtin_amdgcn_fdot2(d, d, san, false);
    d = a1.b - n1.b; san = __builtin_amdgcn_fdot2(d, d, san, false);
    d = a1.c - n1.c; san = __builtin_amdgcn_fdot2(d, d, san, false);
    d = a1.d - n1.d; san = __builtin_amdgcn_fdot2(d, d, san, false);

    #pragma unroll
    for (int o = 4; o; o >>= 1) {
        sap += __shfl_xor(sap, o);
        san += __shfl_xor(san, o);
    }

    if (s == 0) {
        const float d_ap = sqrtf(sap + EPS_F);
        const float d_an = sqrtf(san + EPS_F);
        const float pl = fmaxf(d_ap - b + MARGIN_F, 0.f);
        const float nl = fmaxf(b - d_an + MARGIN_F, 0.f);
        lt += pl + nl;
        lc += (pl > 0.f || nl > 0.f) ? 1.f : 0.f;
    }
}

// ws layout: ws[c*8 + j], j<4: totals, j>=4: counts
__global__ __launch_bounds__(256) void margin_main(
    const _Float16* __restrict__ hb,
    const int* __restrict__ triplets,
    const float* __restrict__ bl,
    float* __restrict__ ws)
{
    __shared__ float s_red[8];
    const int tid  = threadIdx.x;
    const int lane = tid & 63;
    const int wave = tid >> 6;
    const int g    = lane >> 3;       // group in wave (8 lanes/triplet)
    const int s    = lane & 7;        // sub-lane in group

    // XCD-pinned k: blocks round-robin over 8 XCDs; 2 XCDs own each k.
    const int xcd      = blockIdx.x & (NXCD - 1);
    const int k        = xcd >> 1;                               // 0..3
    const int blk_in_k = ((xcd & 1) << 8) | (blockIdx.x >> 3);   // 0..511

    const int g0 = blk_in_k * 32 + wave * 8 + g;

    const int* __restrict__ trip_k = triplets + k * (TT * 3);
    const float* __restrict__ bl_k = bl + k * NN;
    const H8* __restrict__ hb8 = (const H8*)hb;

    float lt = 0.f, lc = 0.f;
    int t = g0;

    // pair-unrolled main loop: 2 triplets' loads in flight per iteration
    for (; t + STRIDE_K < TT; t += 2 * STRIDE_K) {
        const int* tpA = trip_k + t * 3;
        const int* tpB = trip_k + (t + STRIDE_K) * 3;
        const int A0 = tpA[0], A1 = tpA[1], A2 = tpA[2];
        const int B0 = tpB[0], B1 = tpB[1], B2 = tpB[2];

        const H8* aA = hb8 + (((A0 << 2) + k) << 4);
        const H8* pA = hb8 + (((A1 << 2) + k) << 4);
        const H8* nA = hb8 + (((A2 << 2) + k) << 4);
        const H8* aB = hb8 + (((B0 << 2) + k) << 4);
        const H8* pB = hb8 + (((B1 << 2) + k) << 4);
        const H8* nB = hb8 + (((B2 << 2) + k) << 4);

        // issue all 12 row loads + 2 beta loads before any compute
        const H8 rA0 = aA[s],     rA1 = aA[8 + s];
        const H8 sA0 = pA[s],     sA1 = pA[8 + s];
        const H8 tA0 = nA[s],     tA1 = nA[8 + s];
        const H8 rB0 = aB[s],     rB1 = aB[8 + s];
        const H8 sB0 = pB[s],     sB1 = pB[8 + s];
        const H8 tB0 = nB[s],     tB1 = nB[8 + s];
        const float bA = bl_k[A0];
        const float bB = bl_k[B0];

        tri_compute(rA0, rA1, sA0, sA1, tA0, tA1, bA, s, lt, lc);
        tri_compute(rB0, rB1, sB0, sB1, tB0, tB1, bB, s, lt, lc);
    }
    if (t < TT) {   // tail single triplet
        const int* tp = trip_k + t * 3;
        const int A0 = tp[0], A1 = tp[1], A2 = tp[2];
        const H8* aA = hb8 + (((A0 << 2) + k) << 4);
        const H8* pA = hb8 + (((A1 << 2) + k) << 4);
        const H8* nA = hb8 + (((A2 << 2) + k) << 4);
        const H8 rA0 = aA[s], rA1 = aA[8 + s];
        const H8 sA0 = pA[s], sA1 = pA[8 + s];
        const H8 tA0 = nA[s], tA1 = nA[8 + s];
        const float bA = bl_k[A0];
        tri_compute(rA0, rA1, sA0, sA1, tA0, tA1, bA, s, lt, lc);
    }

    // combine the 8 s==0 lanes of this wave (others hold zeros)
    #pragma unroll
    for (int o = 8; o <= 32; o <<= 1) {
        lt += __shfl_xor(lt, o);
        lc += __shfl_xor(lc, o);
    }
    if (lane == 0) { s_red[wave] = lt; s_red[4 + wave] = lc; }
    __syncthreads();

    if (tid == 0) {
        const float tot = s_red[0] + s_red[1] + s_red[2] + s_red[3];
        const float cnt = s_red[4] + s_red[5] + s_red[6] + s_red[7];
        const int c = (blockIdx.x >> 3) & (NCOPY - 1);
        atomicAdd(&ws[c * 8 + k], tot);
        atomicAdd(&ws[c * 8 + 4 + k], cnt);
    }
}

__global__ void margin_final(const float* __restrict__ ws, float* __restrict__ out) {
    if (threadIdx.x == 0 && blockIdx.x == 0) {
        float acc = 0.f;
        #pragma unroll
        for (int k = 0; k < KK; ++k) {
            float tot = 0.f, cnt = 0.f;
            #pragma unroll
            for (int c = 0; c < NCOPY; ++c) {
                tot += ws[c * 8 + k];
                cnt += ws[c * 8 + 4 + k];
            }
            const float lk = (cnt == 0.f) ? tot : tot / fmaxf(cnt, 1.f);
            acc += lk;
        }
        out[0] = acc / (float)KK;
    }
}

extern "C" void kernel_launch(void* const* d_in, const int* in_sizes, int n_in,
                              void* d_out, int out_size, void* d_ws, size_t ws_size,
                              hipStream_t stream) {
    const float* batch    = (const float*)d_in[0];
    const int*   labels   = (const int*)d_in[1];
    const int*   triplets = (const int*)d_in[2];
    const float* beta     = (const float*)d_in[3];

    float*     ws = (float*)d_ws;
    _Float16*  hb = (_Float16*)((char*)d_ws + ACC_BYTES);
    float*     bl = (float*)((char*)d_ws + ACC_BYTES + HB_BYTES);

    prep<<<1024, 256, 0, stream>>>(batch, labels, beta, hb, bl, ws);
    margin_main<<<NBLOCKS, 256, 0, stream>>>(hb, triplets, bl, ws);
    margin_final<<<1, 64, 0, stream>>>(ws, (float*)d_out);
}